// Round 11
// baseline (72862.933 us; speedup 1.0000x reference)
//
#include <hip/hip_runtime.h>
#include <math.h>

// EncoderDecoder LSTM seq2seq, f32 throughout.
// v9: persistent-block design WITHOUT cooperative API (ROCm 7.2 clang-22
// segfaulted on both cg headers and hipLaunchCooperativeKernel; device
// compile of one giant kernel was the other suspect -- both removed).
// Two plain kernels (encoder, decoder), 256 blocks x 512 thr each;
// __noinline__ phase bodies keep each __global__ small. Co-residency by
// capacity: 58.5KB LDS, 8 waves, VGPR<=128 -> >=2 blocks/CU capacity,
// 256 blocks always resident -> hand-rolled grid barrier is safe.
// Phase bodies = proven v2-r3 structures (16.8 ms over 513 dispatches).

#define BB    32
#define SEQ   128
#define HID   1024
#define NV    32000
#define TDEC  64
#define NBLK  256
#define NUNIT 500

__device__ __forceinline__ float sgm(float x) { return 1.0f / (1.0f + expf(-x)); }
__device__ __forceinline__ float dot4(float4 a, float4 b) {
    return a.x*b.x + a.y*b.y + a.z*b.z + a.w*b.w;
}

// ---- grid barrier: monotonic counter, agent scope ----
__device__ __noinline__ void gsync(unsigned* bar, unsigned target) {
    __threadfence();      // release my writes device-wide
    __syncthreads();      // all threads in block have fenced
    if (threadIdx.x == 0) {
        __hip_atomic_fetch_add(bar, 1u, __ATOMIC_RELEASE, __HIP_MEMORY_SCOPE_AGENT);
        while (__hip_atomic_load(bar, __ATOMIC_ACQUIRE, __HIP_MEMORY_SCOPE_AGENT) < target)
            __builtin_amdgcn_s_sleep(1);
    }
    __syncthreads();      // block released by leader
    __threadfence();      // acquire: see remote writes
}

// shared-memory float offsets (union of cell and logits layouts)
#define C_WCH  0        // [16][256] W tile (2 units x 8 gate-rows)
#define C_ACH  4096     // [32][256] activations
#define C_PART 12288    // [4][8][32] split-K partials
#define C_GS   13312    // [8][32] reduced gates
#define C_PVR  13568    // [16][32] argmax partial vals
#define C_PIR  14080    // [16][32] argmax partial idx (int)
#define C_TOK  14592    // [32] tokens (int)
#define L_WCH  0        // [64][128]
#define L_ACH  8192     // [32][128]
#define L_RV   12288    // [16][32]
#define L_RI   12800    // [16][32] int
#define SMEMF  14624    // 58,496 B < 64KB

// ---------------------------------------------------------------------------
// One LSTM layer step. Block does j-cols {2*bid, 2*bid+1} and {+512, +513}.
// Thread map (v2-r3): b=tid&31, ks=(tid>>5)&3 (4-way K split), ng=tid>>7.
// LDS W row r (0..15): unit=r>>3, rr=r&7 -> global row j0u + (rr>>2) + (rr&3)*HID.
// ---------------------------------------------------------------------------
template <int XK>
__device__ __noinline__ void cell_phase(
    float* smem, int bid, int tid,
    const float* __restrict__ xdir,          // [BB][XK] (layer-1 path)
    const float* __restrict__ emb,           // [V][XK] (embedding path)
    const int*   __restrict__ xtok, int xoff,// token from x[b*SEQ+xoff]
    int constTok,                            // or constant token (BOS)
    const float* __restrict__ pval, const int* __restrict__ pidx, // or argmax
    const float* __restrict__ Wih, const float* __restrict__ Whh,
    const float* __restrict__ bias,
    const float* __restrict__ h_in, float* __restrict__ h_out,
    float* __restrict__ c_st)
{
    constexpr int NCH = (XK + HID) / 256;
    float* Wch  = smem + C_WCH;
    float* Ach  = smem + C_ACH;
    float* part = smem + C_PART;
    float* gs   = smem + C_GS;
    float* pvr  = smem + C_PVR;
    int*   pir  = (int*)(smem + C_PIR);
    int*   tokl = (int*)(smem + C_TOK);

    const int b  = tid & 31;
    const int ks = (tid >> 5) & 3;
    const int ng = tid >> 7;

    // ---- resolve tokens (once; shared by both units) ----
    if (emb) {
        if (pval) {
            const int pg = tid >> 5;
            float bv = -3.402823e38f; int bi = 0x7fffffff;
            for (int p = pg; p < NUNIT; p += 16) {
                const float v = pval[p * 32 + b];
                const int  ix = pidx[p * 32 + b];
                if (v > bv || (v == bv && ix < bi)) { bv = v; bi = ix; }
            }
            pvr[pg * 32 + b] = bv; pir[pg * 32 + b] = bi;
            __syncthreads();
            if (tid < 32) {
                float v0 = pvr[tid]; int i0 = pir[tid];
                #pragma unroll
                for (int g = 1; g < 16; ++g) {
                    const float v = pvr[g * 32 + tid];
                    const int  ix = pir[g * 32 + tid];
                    if (v > v0 || (v == v0 && ix < i0)) { v0 = v; i0 = ix; }
                }
                tokl[tid] = i0;
            }
            __syncthreads();
        } else {
            if (tid < 32) tokl[tid] = xtok ? xtok[tid * SEQ + xoff] : constTok;
            __syncthreads();
        }
    }

    // ---- staging coords ----
    const int ar = tid >> 4, al = tid & 15;       // A: row, 4 quads al+16i
    const int asw = (ar & 7) << 2;                // source-side swizzle
    const int wr = tid >> 5;                      // LDS W row 0..15
    const int wl = tid & 31;                      // quads wl, wl+32
    const int rr = wr & 7;
    const int j0u_w = 2 * bid + 512 * (wr >> 3);
    const int wrow_g = j0u_w + (rr >> 2) + (rr & 3) * HID;

    const float* arowx = emb ? (emb + (size_t)tokl[ar] * XK)
                             : (xdir + (size_t)ar * XK);
    const float* arowh = h_in + (size_t)ar * HID;
    const int bsw = (b & 7) << 2;

    float acc[2][2] = {{0.0f, 0.0f}, {0.0f, 0.0f}};  // [unit][row-pair]

    for (int ch = 0; ch < NCH; ++ch) {
        const int kb0 = ch * 256;   // chunk never straddles the XK boundary

        const float* as = (kb0 < XK) ? (arowx + kb0) : (arowh + (kb0 - XK));
        float4 aR[4];
        #pragma unroll
        for (int i = 0; i < 4; ++i)
            aR[i] = *reinterpret_cast<const float4*>(as + (((al + 16 * i) * 4) ^ asw));
        const float* wsp = (kb0 < XK) ? (Wih + (size_t)wrow_g * XK + kb0)
                                      : (Whh + (size_t)wrow_g * HID + (kb0 - XK));
        const float4 wv0 = *reinterpret_cast<const float4*>(wsp + wl * 4);
        const float4 wv1 = *reinterpret_cast<const float4*>(wsp + (wl + 32) * 4);

        __syncthreads();   // previous chunk's readers done
        #pragma unroll
        for (int i = 0; i < 4; ++i)
            *reinterpret_cast<float4*>(&Ach[ar * 256 + (al + 16 * i) * 4]) = aR[i];
        *reinterpret_cast<float4*>(&Wch[wr * 256 + wl * 4]) = wv0;
        *reinterpret_cast<float4*>(&Wch[wr * 256 + (wl + 32) * 4]) = wv1;
        __syncthreads();

        const int kb = ks * 64;
        #pragma unroll
        for (int kk = 0; kk < 64; kk += 4) {
            const float4 a = *reinterpret_cast<const float4*>(
                &Ach[b * 256 + ((kb + kk) ^ bsw)]);
            #pragma unroll
            for (int u = 0; u < 2; ++u) {
                #pragma unroll
                for (int p = 0; p < 2; ++p) {
                    const int r = u * 8 + ng * 2 + p;
                    const float4 wv = *reinterpret_cast<const float4*>(
                        &Wch[r * 256 + kb + kk]);
                    acc[u][p] += dot4(a, wv);
                }
            }
        }
    }

    // ---- per-unit split-K reduce + pointwise ----
    #pragma unroll
    for (int u = 0; u < 2; ++u) {
        __syncthreads();
        part[(ks * 8 + ng * 2 + 0) * 32 + b] = acc[u][0];
        part[(ks * 8 + ng * 2 + 1) * 32 + b] = acc[u][1];
        __syncthreads();
        if (tid < 256) {
            const int r = tid >> 5, b2 = tid & 31;
            float s = 0.0f;
            #pragma unroll
            for (int k2 = 0; k2 < 4; ++k2) s += part[(k2 * 8 + r) * 32 + b2];
            gs[r * 32 + b2] = s;
        }
        __syncthreads();
        if (tid < 64) {
            const int fb = tid & 31, jl = tid >> 5;
            const int j = 2 * bid + 512 * u + jl;
            float g4[4];
            #pragma unroll
            for (int g = 0; g < 4; ++g)
                g4[g] = gs[(jl * 4 + g) * 32 + fb] + bias[j + g * HID];
            const float cp = c_st[fb * HID + j];
            const float cn = sgm(g4[1]) * cp + sgm(g4[0]) * tanhf(g4[2]);
            const float hn = sgm(g4[3]) * tanhf(cn);
            c_st[fb * HID + j]  = cn;
            h_out[fb * HID + j] = hn;
        }
    }
}

// ---------------------------------------------------------------------------
// Logits + per-unit argmax partials (v2-r3 body; up to 2 units per block).
// ---------------------------------------------------------------------------
__device__ __noinline__ void logits_phase(
    float* smem, int bid, int tid,
    const float* __restrict__ h1, const float* __restrict__ W,
    const float* __restrict__ bias,
    float* __restrict__ out, int t,
    float* __restrict__ pval, int* __restrict__ pidx)
{
    float* Wch = smem + L_WCH;
    float* Ach = smem + L_ACH;
    float* rv  = smem + L_RV;
    int*   ri  = (int*)(smem + L_RI);

    const int b  = tid & 31;
    const int vs = tid >> 5;                  // 0..15, 4 v each
    const int sro = tid >> 5, scq = tid & 31; // staging: rows sro+16i
    const int bsw = (b & 7) << 2;

    for (int u = bid; u < NUNIT; u += NBLK) {
        const int v0 = u * 64;
        float acc[4] = {0.f, 0.f, 0.f, 0.f};

        for (int ch = 0; ch < 8; ++ch) {
            const int k0 = ch * 128;
            float4 wR[4], aR[2];
            #pragma unroll
            for (int i = 0; i < 4; ++i)
                wR[i] = *reinterpret_cast<const float4*>(
                    W + (size_t)(v0 + sro + 16 * i) * HID + k0 + scq * 4);
            #pragma unroll
            for (int i = 0; i < 2; ++i) {
                const int row = sro + 16 * i;
                const int sw = (row & 7) << 2;
                aR[i] = *reinterpret_cast<const float4*>(
                    h1 + (size_t)row * HID + k0 + ((scq * 4) ^ sw));
            }
            __syncthreads();
            #pragma unroll
            for (int i = 0; i < 4; ++i)
                *reinterpret_cast<float4*>(&Wch[(sro + 16 * i) * 128 + scq * 4]) = wR[i];
            #pragma unroll
            for (int i = 0; i < 2; ++i)
                *reinterpret_cast<float4*>(&Ach[(sro + 16 * i) * 128 + scq * 4]) = aR[i];
            __syncthreads();
            #pragma unroll
            for (int kk = 0; kk < 128; kk += 4) {
                const float4 av = *reinterpret_cast<const float4*>(
                    &Ach[b * 128 + (kk ^ bsw)]);
                #pragma unroll
                for (int i = 0; i < 4; ++i) {
                    const float4 wf = *reinterpret_cast<const float4*>(
                        &Wch[(vs * 4 + i) * 128 + kk]);
                    acc[i] += dot4(av, wf);
                }
            }
        }

        // bias + output + argmax partial (ascending v -> first-max tie-break)
        const int vbase = v0 + vs * 4;
        float res[4];
        float bestv = -3.402823e38f;
        int   besti = 0;
        #pragma unroll
        for (int i = 0; i < 4; ++i) {
            res[i] = acc[i] + bias[vbase + i];
            if (res[i] > bestv) { bestv = res[i]; besti = vbase + i; }
        }
        *reinterpret_cast<float4*>(&out[((size_t)b * TDEC + t) * (size_t)NV + vbase]) =
            make_float4(res[0], res[1], res[2], res[3]);
        rv[vs * 32 + b] = bestv;
        ri[vs * 32 + b] = besti;
        __syncthreads();
        if (tid < 32) {
            float bv = rv[tid]; int bi = ri[tid];
            #pragma unroll
            for (int g = 1; g < 16; ++g) {
                const float v = rv[g * 32 + tid];
                const int  ix = ri[g * 32 + tid];
                if (v > bv || (v == bv && ix < bi)) { bv = v; bi = ix; }
            }
            pval[u * 32 + tid] = bv;
            pidx[u * 32 + tid] = bi;
        }
        __syncthreads();   // rv/ri + Wch free before next unit
    }
}

// ---------------------------------------------------------------------------
__global__ void __launch_bounds__(512) enc_kernel(
    const int* x, const float* enc_emb,
    const float* eWih0, const float* eWhh0, const float* eb0,
    const float* eWih1, const float* eWhh1, const float* eb1,
    float* h0a, float* h0b, float* c0, float* h1a, float* h1b, float* c1,
    unsigned* bar)
{
    __shared__ float smem[SMEMF];
    const int bid = blockIdx.x, tid = threadIdx.x;
    unsigned nsync = 0;

    // zero-init state (poisoned workspace)
    for (int i = bid * 512 + tid; i < BB * HID; i += NBLK * 512) {
        h0a[i] = 0.f; c0[i] = 0.f; h1a[i] = 0.f; c1[i] = 0.f;
    }
    gsync(bar, ++nsync * NBLK);

    float* h0buf[2] = { h0a, h0b };
    float* h1buf[2] = { h1a, h1b };

    for (int t = 0; t < SEQ; ++t) {
        cell_phase<512>(smem, bid, tid, nullptr, enc_emb, x, t, -1, nullptr, nullptr,
                        eWih0, eWhh0, eb0, h0buf[t & 1], h0buf[(t + 1) & 1], c0);
        gsync(bar, ++nsync * NBLK);
        cell_phase<1024>(smem, bid, tid, h0buf[(t + 1) & 1], nullptr, nullptr, 0, -1,
                         nullptr, nullptr,
                         eWih1, eWhh1, eb1, h1buf[t & 1], h1buf[(t + 1) & 1], c1);
        gsync(bar, ++nsync * NBLK);
    }
}

__global__ void __launch_bounds__(512) dec_kernel(
    const float* dec_emb,
    const float* dWih0, const float* dWhh0, const float* db0,
    const float* dWih1, const float* dWhh1, const float* db1,
    const float* pW, const float* pb, float* out,
    float* h0a, float* h0b, float* c0, float* h1a, float* h1b, float* c1,
    float* pval, int* pidx, unsigned* bar)
{
    __shared__ float smem[SMEMF];
    const int bid = blockIdx.x, tid = threadIdx.x;
    unsigned nsync = 0;

    float* h0buf[2] = { h0a, h0b };
    float* h1buf[2] = { h1a, h1b };

    // encoder ran SEQ=128 (even) steps: its final h is in h0buf[0]/h1buf[0],
    // so decoder parity continues from t=0.
    for (int t = 0; t < TDEC; ++t) {
        if (t == 0) {
            cell_phase<1024>(smem, bid, tid, nullptr, dec_emb, nullptr, 0, 1,
                             nullptr, nullptr,
                             dWih0, dWhh0, db0, h0buf[t & 1], h0buf[(t + 1) & 1], c0);
        } else {
            cell_phase<1024>(smem, bid, tid, nullptr, dec_emb, nullptr, 0, -1,
                             pval, pidx,
                             dWih0, dWhh0, db0, h0buf[t & 1], h0buf[(t + 1) & 1], c0);
        }
        gsync(bar, ++nsync * NBLK);
        cell_phase<1024>(smem, bid, tid, h0buf[(t + 1) & 1], nullptr, nullptr, 0, -1,
                         nullptr, nullptr,
                         dWih1, dWhh1, db1, h1buf[t & 1], h1buf[(t + 1) & 1], c1);
        gsync(bar, ++nsync * NBLK);
        logits_phase(smem, bid, tid, h1buf[(t + 1) & 1], pW, pb, out, t, pval, pidx);
        gsync(bar, ++nsync * NBLK);
    }
}

// ---------------------------------------------------------------------------
extern "C" void kernel_launch(void* const* d_in, const int* in_sizes, int n_in,
                              void* d_out, int out_size, void* d_ws, size_t ws_size,
                              hipStream_t stream)
{
    const int*   x       = (const int*)  d_in[0];
    const float* enc_emb = (const float*)d_in[1];
    const float* dec_emb = (const float*)d_in[2];
    const float* eWih0   = (const float*)d_in[3];
    const float* eWhh0   = (const float*)d_in[4];
    const float* eb0     = (const float*)d_in[5];
    const float* eWih1   = (const float*)d_in[6];
    const float* eWhh1   = (const float*)d_in[7];
    const float* eb1     = (const float*)d_in[8];
    const float* dWih0   = (const float*)d_in[9];
    const float* dWhh0   = (const float*)d_in[10];
    const float* db0     = (const float*)d_in[11];
    const float* dWih1   = (const float*)d_in[12];
    const float* dWhh1   = (const float*)d_in[13];
    const float* db1     = (const float*)d_in[14];
    const float* pW      = (const float*)d_in[15];
    const float* pb      = (const float*)d_in[16];
    float* out = (float*)d_out;

    float* w    = (float*)d_ws;
    float* h0a  = w;
    float* h0b  = w + 32768;
    float* c0   = w + 65536;
    float* h1a  = w + 98304;
    float* h1b  = w + 131072;
    float* c1   = w + 163840;
    float* pval = w + 196608;                     // [500][32]
    int*   pidx = (int*)(w + 196608 + 16000);     // [500][32]
    unsigned* bar = (unsigned*)(w + 196608 + 32000);  // [2]

    hipMemsetAsync(bar, 0, 2 * sizeof(unsigned), stream);

    enc_kernel<<<dim3(NBLK), dim3(512), 0, stream>>>(
        x, enc_emb, eWih0, eWhh0, eb0, eWih1, eWhh1, eb1,
        h0a, h0b, c0, h1a, h1b, c1, bar + 0);

    dec_kernel<<<dim3(NBLK), dim3(512), 0, stream>>>(
        dec_emb, dWih0, dWhh0, db0, dWih1, dWhh1, db1, pW, pb, out,
        h0a, h0b, c0, h1a, h1b, c1, pval, pidx, bar + 1);
}